// Round 9
// baseline (184.606 us; speedup 1.0000x reference)
//
#include <hip/hip_runtime.h>
#include <hip/hip_bf16.h>
#include <hip/hip_fp16.h>

typedef _Float16 f16;
typedef f16 f16x8 __attribute__((ext_vector_type(8)));
typedef f16 f16x4 __attribute__((ext_vector_type(4)));
typedef f16 f16x2 __attribute__((ext_vector_type(2)));
typedef float f32x4 __attribute__((ext_vector_type(4)));
typedef float f32x16 __attribute__((ext_vector_type(16)));
typedef unsigned int u32x4 __attribute__((ext_vector_type(4)));
typedef unsigned int u32x2 __attribute__((ext_vector_type(2)));

#define MFMA16(a, b, c) __builtin_amdgcn_mfma_f32_16x16x32_f16(a, b, c, 0, 0, 0)
#define MFMA32(a, b, c) __builtin_amdgcn_mfma_f32_32x32x16_f16(a, b, c, 0, 0, 0)

constexpr int BB = 4, SS = 2048, DD = 1024, HH = 16, HDIM = 64;
constexpr int MM = BB * SS; // 8192
// fold 1/sqrt(Hd) and ln->log2 conversion into Q so softmax uses exp2 directly
constexpr float QSCALE = 0.125f * 1.44269504088896340736f;

// K/V are stored CHUNK-TILED: 16B chunk (bh, tile, slot, row) at f16 offset
//   (((bh*32 + tile)*8 + slot)*64 + row) * 8
// K chunk holds K[s = tile*64 + row][hd = slot*8 .. +7]
// V chunk holds V^T[hd = row][k = tile*64 + slot*8 .. +7]
// -> attn MFMA fragments are lane-consecutive 16B chunks in GLOBAL memory:
//    loaded straight to VGPRs (no LDS, no barriers); L1 serves 4-wave reuse.

// async global->LDS, 16B per lane; LDS dst is WAVE-UNIFORM base (HW adds lane*16B)
__device__ __forceinline__ void gl_lds16(const void* g, void* l) {
  __builtin_amdgcn_global_load_lds((const __attribute__((address_space(1))) void*)g,
                                   (__attribute__((address_space(3))) void*)l, 16, 0, 0);
}

// ---------------- fp32 -> f16 conversion (x + 4 weights, one launch) ----------------
__global__ __launch_bounds__(256) void cvt_all_kernel(const float* __restrict__ x,
                                                      const float* __restrict__ w0,
                                                      const float* __restrict__ w1,
                                                      const float* __restrict__ w2,
                                                      const float* __restrict__ w3,
                                                      f16* xh, f16* o0, f16* o1,
                                                      f16* o2, f16* o3) {
  int bid = blockIdx.x;
  const float* in; f16* out; int idx;
  if (bid < MM * DD / 4 / 256) {          // 8192 blocks for x
    in = x; out = xh; idx = bid * 256 + threadIdx.x;
  } else {
    int wb = bid - MM * DD / 4 / 256;     // 4 x 1024 blocks for weights
    int which = wb >> 10;
    in = which == 0 ? w0 : which == 1 ? w1 : which == 2 ? w2 : w3;
    out = which == 0 ? o0 : which == 1 ? o1 : which == 2 ? o2 : o3;
    idx = (wb & 1023) * 256 + threadIdx.x;
  }
  f32x4 v = reinterpret_cast<const f32x4*>(in)[idx];
  f16x4 o;
  o[0] = (f16)v[0]; o[1] = (f16)v[1]; o[2] = (f16)v[2]; o[3] = (f16)v[3];
  reinterpret_cast<f16x4*>(out)[idx] = o;
}

// swizzled LDS offset for 64-f16-wide rows (8 slots of 16B), row in f16 units
__device__ __forceinline__ int swz(int row, int slot) {
  return row * 64 + ((slot ^ (row & 7)) << 3);
}

// ---------------- fused QKV GEMM ----------------
// Q -> [bh][s][hd] (scaled); K -> chunk-tiled; V -> chunk-tiled transposed
// flat grid 1536, XCD-swizzled so blocks sharing an A-panel land on one XCD
__global__ __launch_bounds__(256) void qkv_kernel(const f16* __restrict__ A,
                                                  const f16* __restrict__ Wq,
                                                  const f16* __restrict__ Wk,
                                                  const f16* __restrict__ Wv,
                                                  const float* __restrict__ bq,
                                                  const float* __restrict__ bk,
                                                  const float* __restrict__ bv,
                                                  f16* __restrict__ Qo,
                                                  f16* __restrict__ Ko,
                                                  f16* __restrict__ Vo) {
  constexpr int K = 1024;
  constexpr int TS = 152;                 // repack stride: 76 dw == 12 mod 32 -> <=4-way
  __shared__ __align__(16) char smem_raw[128 * TS * 2];   // 38 KB
  f16* As = (f16*)smem_raw;
  f16* Ws = As + 128 * 64;

  // XCD swizzle: same-y (shared A-panel) -> same XCD (p & 7 fixed per y%8)
  const int p = blockIdx.x;
  const int bx = (p >> 3) % 24;           // 0..23
  const int by = (p & 7) + 8 * ((p >> 3) / 24);

  const int mat = bx >> 3;                // 0:Q 1:K 2:V
  const f16* W = mat == 0 ? Wq : (mat == 1 ? Wk : Wv);
  const float* bias = mat == 0 ? bq : (mat == 1 ? bk : bv);
  const float scale = mat == 0 ? QSCALE : 1.0f;

  const int tid = threadIdx.x;
  const int m0 = by * 128, n0 = (bx & 7) * 128;
  const int w = tid >> 6, lane = tid & 63;
  const int wm = (w >> 1) * 64, wn = (w & 1) * 64;
  const int g = lane >> 4, r = lane & 15;
  const int srow = lane >> 3;
  const int sslot = (lane & 7) ^ srow;

  f32x4 acc[4][4] = {};

  for (int k0 = 0; k0 < K; k0 += 64) {
#pragma unroll
    for (int i = 0; i < 4; ++i) {
      int rbase = w * 32 + i * 8;
      gl_lds16(A + (size_t)(m0 + rbase + srow) * K + k0 + sslot * 8, As + rbase * 64);
      gl_lds16(W + (size_t)(n0 + rbase + srow) * K + k0 + sslot * 8, Ws + rbase * 64);
    }
    __syncthreads();

#pragma unroll
    for (int ks = 0; ks < 2; ++ks) {
      f16x8 af[4], bf[4];
#pragma unroll
      for (int i = 0; i < 4; ++i) {
        af[i] = *reinterpret_cast<const f16x8*>(As + swz(wm + i * 16 + r, (ks << 2) | g));
        bf[i] = *reinterpret_cast<const f16x8*>(Ws + swz(wn + i * 16 + r, (ks << 2) | g));
      }
#pragma unroll
      for (int i = 0; i < 4; ++i)
#pragma unroll
        for (int j = 0; j < 4; ++j)
          acc[i][j] = MFMA16(af[i], bf[j], acc[i][j]);
    }
    __syncthreads();
  }

  if (mat == 0) {
#pragma unroll
    for (int i = 0; i < 4; ++i)
#pragma unroll
      for (int j = 0; j < 4; ++j)
#pragma unroll
        for (int q = 0; q < 4; ++q) {
          int gm = m0 + wm + i * 16 + g * 4 + q;
          int gn = n0 + wn + j * 16 + r;
          float v = (acc[i][j][q] + bias[gn]) * scale;
          int b = gm >> 11, s = gm & 2047;
          int h = gn >> 6, hd = gn & 63;
          Qo[(((size_t)(b * HH + h)) * SS + s) * HDIM + hd] = (f16)v;
        }
  } else if (mat == 1) {
    // K: repack through LDS (row-major), then coalesced 16B chunk stores
    __syncthreads();
    f16* T = (f16*)smem_raw;               // [128 m=s][TS n=feature]
#pragma unroll
    for (int i = 0; i < 4; ++i)
#pragma unroll
      for (int j = 0; j < 4; ++j)
#pragma unroll
        for (int q = 0; q < 4; ++q) {
          int ml = wm + i * 16 + g * 4 + q;
          int nl = wn + j * 16 + r;
          T[ml * TS + nl] = (f16)(acc[i][j][q] + bias[n0 + nl]);
        }
    __syncthreads();
    const int b = m0 >> 11, sbase = m0 & 2047;
#pragma unroll
    for (int it = 0; it < 8; ++it) {
      int cid = it * 256 + tid;            // 2048 chunks: 128 s x 16 feature-slots
      int row_s = cid & 127, ns = cid >> 7;
      u32x4 v = *reinterpret_cast<const u32x4*>(T + row_s * TS + ns * 8);
      int gn0 = n0 + ns * 8;
      int h = gn0 >> 6, slot = (gn0 & 63) >> 3;
      int tile = (sbase >> 6) + (row_s >> 6), row = row_s & 63;
      size_t off = ((((size_t)(b * HH + h) * 32 + tile) * 8 + slot) * 64 + row) * 8;
      *reinterpret_cast<u32x4*>(Ko + off) = v;
    }
  } else {
    // V: transpose through LDS, then coalesced chunk-tiled stores
    __syncthreads();
    f16* T = (f16*)smem_raw;               // [128 n=hd][TS m=s]
#pragma unroll
    for (int i = 0; i < 4; ++i)
#pragma unroll
      for (int j = 0; j < 4; ++j)
#pragma unroll
        for (int q = 0; q < 4; ++q) {
          int ml = wm + i * 16 + g * 4 + q;
          int nl = wn + j * 16 + r;
          T[nl * TS + ml] = (f16)(acc[i][j][q] + bias[n0 + nl]);
        }
    __syncthreads();
    const int b = m0 >> 11, sbase = m0 & 2047;
#pragma unroll
    for (int it = 0; it < 8; ++it) {
      int cid = it * 256 + tid;            // 2048 chunks: 2 tiles x 8 slots x 128 hd
      int hd_l = cid & 127, sl = (cid >> 7) & 7, tl = cid >> 10;
      u32x4 v = *reinterpret_cast<const u32x4*>(T + hd_l * TS + tl * 64 + sl * 8);
      int gn = n0 + hd_l, h = gn >> 6, hd = gn & 63;
      int tile = (sbase >> 6) + tl;
      size_t off = ((((size_t)(b * HH + h) * 32 + tile) * 8 + sl) * 64 + hd) * 8;
      *reinterpret_cast<u32x4*>(Vo + off) = v;
    }
  }
}

// ---------------- output projection GEMM (fp32 out), flat grid 512 XCD-swizzled ----------------
__global__ __launch_bounds__(256) void oproj_kernel(const f16* __restrict__ A,
                                                    const f16* __restrict__ W,
                                                    const float* __restrict__ bias,
                                                    float* __restrict__ Out) {
  constexpr int K = 1024, N = 1024;
  __shared__ __align__(16) f16 As[128 * 64];
  __shared__ __align__(16) f16 Ws[128 * 64];

  const int p = blockIdx.x;
  const int bx = (p >> 3) & 7;
  const int by = (p & 7) | ((p >> 6) << 3);

  const int tid = threadIdx.x;
  const int m0 = by * 128, n0 = bx * 128;
  const int w = tid >> 6, lane = tid & 63;
  const int wm = (w >> 1) * 64, wn = (w & 1) * 64;
  const int g = lane >> 4, r = lane & 15;
  const int srow = lane >> 3;
  const int sslot = (lane & 7) ^ srow;

  f32x4 acc[4][4] = {};

  for (int k0 = 0; k0 < K; k0 += 64) {
#pragma unroll
    for (int i = 0; i < 4; ++i) {
      int rbase = w * 32 + i * 8;
      gl_lds16(A + (size_t)(m0 + rbase + srow) * K + k0 + sslot * 8, As + rbase * 64);
      gl_lds16(W + (size_t)(n0 + rbase + srow) * K + k0 + sslot * 8, Ws + rbase * 64);
    }
    __syncthreads();

#pragma unroll
    for (int ks = 0; ks < 2; ++ks) {
      f16x8 af[4], bf[4];
#pragma unroll
      for (int i = 0; i < 4; ++i) {
        af[i] = *reinterpret_cast<const f16x8*>(As + swz(wm + i * 16 + r, (ks << 2) | g));
        bf[i] = *reinterpret_cast<const f16x8*>(Ws + swz(wn + i * 16 + r, (ks << 2) | g));
      }
#pragma unroll
      for (int i = 0; i < 4; ++i)
#pragma unroll
        for (int j = 0; j < 4; ++j)
          acc[i][j] = MFMA16(af[i], bf[j], acc[i][j]);
    }
    __syncthreads();
  }

#pragma unroll
  for (int i = 0; i < 4; ++i)
#pragma unroll
    for (int j = 0; j < 4; ++j)
#pragma unroll
      for (int q = 0; q < 4; ++q) {
        int gm = m0 + wm + i * 16 + g * 4 + q;
        int gn = n0 + wn + j * 16 + r;
        Out[(size_t)gm * N + gn] = acc[i][j][q] + bias[gn];
      }
}

// ---------------- flash attention: barrier-free, L1/L2-direct fragments ----------------
// All K/V MFMA fragments are coalesced 16B global chunks (see layout above) and
// identical across the 4 waves of a block -> L1 serves the reuse; no LDS staging,
// no __syncthreads. Register ping-pong: each frag set reissued for tile t+1 right
// after its consuming MFMA cluster (load-to-use ~2 phases >> L2 latency).
// flat grid 512 (8 q-blocks x 64 bh), XCD-swizzled: same-bh -> same XCD
__global__ __launch_bounds__(256, 2) void attn_kernel(const f16* __restrict__ Q,
                                                      const f16* __restrict__ K,
                                                      const f16* __restrict__ Vt,
                                                      f16* __restrict__ AO) {
  __shared__ float Lw[4][64];

  const int p = blockIdx.x;
  const int qx = (p >> 3) & 7;
  const int bh = (p & 7) | ((p >> 6) << 3);
  const int q0 = qx * 256;

  const int tid = threadIdx.x;
  const int w = tid >> 6, lane = tid & 63;
  const int q31 = lane & 31;          // q row within each 32x32 sub-tile / hd col
  const int h = lane >> 5;            // wave half

  // lane-fragment base pointers (f16 units); tile stride = 4096 f16
  const f16* Kl = K + (size_t)bh * (SS * HDIM) + h * 512 + q31 * 8;
  const f16* Vl = Vt + (size_t)bh * (SS * HDIM) + h * 512 + q31 * 8;

  // Q B-fragments: qf[f][m][e] = Q[q0 + 64w + 32f + q31][16m + 8h + e]
  const f16* Qg = Q + ((size_t)bh * SS + q0 + w * 64 + q31) * HDIM + 8 * h;
  f16x8 qf[2][4];
#pragma unroll
  for (int f = 0; f < 2; ++f)
#pragma unroll
    for (int m = 0; m < 4; ++m)
      qf[f][m] = *reinterpret_cast<const f16x8*>(Qg + f * 32 * HDIM + 16 * m);

  f32x16 oacc[2][2] = {};   // [f][vb]: O[q(regs)][hd = 32vb + q31]
  float lsum0 = 0.f, lsum1 = 0.f;
  unsigned pkP0[8], pkP1[8];    // pending P (written by SM, consumed by next PV)

  // fragment registers: kA = K(t,kb0) m=0..3; kB = K(t,kb1); vLo = V(t) j=0,1;
  // vHi = V(t-1 at phase A / t after reissue) j=2,3.  Each entry = one 16B chunk.
  u32x4 kA[4], kB[4], vLo[4], vHi[4];

#define LD16(PTR) (*reinterpret_cast<const u32x4*>(PTR))

  // prologue: tile 0 K frags + V low half
#pragma unroll
  for (int m = 0; m < 4; ++m) kA[m] = LD16(Kl + m * 1024);
#pragma unroll
  for (int m = 0; m < 4; ++m) kB[m] = LD16(Kl + m * 1024 + 256);
#pragma unroll
  for (int jl = 0; jl < 2; ++jl)
#pragma unroll
    for (int vb = 0; vb < 2; ++vb)
      vLo[2 * jl + vb] = LD16(Vl + jl * 1024 + vb * 256);

#define PV_CLUSTER(VREG)                                                                 \
  do {                                                                                   \
    _Pragma("unroll") for (int jl = 0; jl < 2; ++jl) {                                   \
      auto a0 = __builtin_amdgcn_permlane32_swap(pkP0[4 * jl + 0], pkP0[4 * jl + 2],     \
                                                 false, false);                          \
      auto a1 = __builtin_amdgcn_permlane32_swap(pkP0[4 * jl + 1], pkP0[4 * jl + 3],     \
                                                 false, false);                          \
      u32x4 fa = {(unsigned)a0[0], (unsigned)a1[0], (unsigned)a0[1], (unsigned)a1[1]};   \
      f16x8 pa0 = __builtin_bit_cast(f16x8, fa);                                         \
      auto b0 = __builtin_amdgcn_permlane32_swap(pkP1[4 * jl + 0], pkP1[4 * jl + 2],     \
                                                 false, false);                          \
      auto b1 = __builtin_amdgcn_permlane32_swap(pkP1[4 * jl + 1], pkP1[4 * jl + 3],     \
                                                 false, false);                          \
      u32x4 fb = {(unsigned)b0[0], (unsigned)b1[0], (unsigned)b0[1], (unsigned)b1[1]};   \
      f16x8 pa1 = __builtin_bit_cast(f16x8, fb);                                         \
      _Pragma("unroll") for (int vb = 0; vb < 2; ++vb) {                                 \
        f16x8 vbf = __builtin_bit_cast(f16x8, (VREG)[2 * jl + vb]);                      \
        oacc[0][vb] = MFMA32(pa0, vbf, oacc[0][vb]);                                     \
        oacc[1][vb] = MFMA32(pa1, vbf, oacc[1][vb]);                                     \
      }                                                                                  \
    }                                                                                    \
  } while (0)

#define SM_CLUSTER(SC0, SC1)                                                             \
  do {                                                                                   \
    _Pragma("unroll") for (int rp = 0; rp < 4; ++rp)                                     \
        _Pragma("unroll") for (int pp = 0; pp < 2; ++pp) {                               \
      float a0 = __builtin_amdgcn_exp2f((SC0)[4 * rp + 2 * pp]);                         \
      float a1 = __builtin_amdgcn_exp2f((SC0)[4 * rp + 2 * pp + 1]);                     \
      pkP0[2 * rp + pp] = __builtin_bit_cast(unsigned, __builtin_amdgcn_cvt_pkrtz(a0, a1));\
      float b0 = __builtin_amdgcn_exp2f((SC1)[4 * rp + 2 * pp]);                         \
      float b1 = __builtin_amdgcn_exp2f((SC1)[4 * rp + 2 * pp + 1]);                     \
      pkP1[2 * rp + pp] = __builtin_bit_cast(unsigned, __builtin_amdgcn_cvt_pkrtz(b0, b1));\
    }                                                                                    \
    {                                                                                    \
      f16x2 u01 = __builtin_bit_cast(f16x2, pkP0[0]) + __builtin_bit_cast(f16x2, pkP0[1]);\
      f16x2 u23 = __builtin_bit_cast(f16x2, pkP0[2]) + __builtin_bit_cast(f16x2, pkP0[3]);\
      f16x2 u45 = __builtin_bit_cast(f16x2, pkP0[4]) + __builtin_bit_cast(f16x2, pkP0[5]);\
      f16x2 u67 = __builtin_bit_cast(f16x2, pkP0[6]) + __builtin_bit_cast(f16x2, pkP0[7]);\
      f16x2 ut = (u01 + u23) + (u45 + u67);                                              \
      lsum0 += (float)ut[0] + (float)ut[1];                                              \
    }                                                                                    \
    {                                                                                    \
      f16x2 u01 = __builtin_bit_cast(f16x2, pkP1[0]) + __builtin_bit_cast(f16x2, pkP1[1]);\
      f16x2 u23 = __builtin_bit_cast(f16x2, pkP1[2]) + __builtin_bit_cast(f16x2, pkP1[3]);\
      f16x2 u45 = __builtin_bit_cast(f16x2, pkP1[4]) + __builtin_bit_cast(f16x2, pkP1[5]);\
      f16x2 u67 = __builtin_bit_cast(f16x2, pkP1[6]) + __builtin_bit_cast(f16x2, pkP1[7]);\
      f16x2 ut = (u01 + u23) + (u45 + u67);                                              \
      lsum1 += (float)ut[0] + (float)ut[1];                                              \
    }                                                                                    \
  } while (0)

  for (int t = 0; t < SS / 64; ++t) {
    const size_t tb = (size_t)t * 4096;
    const size_t tn = tb + 4096;

    // ---- phase A: QK(kb0) + PV(kb1 of tile t-1, vHi) + SM0
    {
      f32x16 sc0 = {}, sc1 = {};
      __builtin_amdgcn_s_setprio(1);
#pragma unroll
      for (int m = 0; m < 4; ++m) {
        f16x8 kf = __builtin_bit_cast(f16x8, kA[m]);
        sc0 = MFMA32(kf, qf[0][m], sc0);
        sc1 = MFMA32(kf, qf[1][m], sc1);
      }
      if (t > 0) PV_CLUSTER(vHi);
      __builtin_amdgcn_s_setprio(0);
      // reissue consumed sets: vHi <- V(t) high half; kA <- K(t+1, kb0)
#pragma unroll
      for (int jl = 0; jl < 2; ++jl)
#pragma unroll
        for (int vb = 0; vb < 2; ++vb)
          vHi[2 * jl + vb] = LD16(Vl + tb + (2 + jl) * 1024 + vb * 256);
      if (t < SS / 64 - 1) {
#pragma unroll
        for (int m = 0; m < 4; ++m) kA[m] = LD16(Kl + tn + m * 1024);
      }
      SM_CLUSTER(sc0, sc1);
    }

    // ---- phase B: QK(kb1) + PV(kb0, vLo = V(t)) + SM1
    {
      f32x16 sc0 = {}, sc1 = {};
      __builtin_amdgcn_s_setprio(1);
#pragma unroll
      for (int m = 0; m < 4; ++m) {
        f16x8 kf = __builtin_bit_cast(f16x8, kB[m]);
        sc0 = MFMA32(kf, qf[0][m], sc0);
        sc1 = MFMA32(kf, qf[1][m], sc1);
      }
      PV_CLUSTER(vLo);
      __builtin_amdgcn_s_setprio(0);
      // reissue consumed sets: kB <- K(t+1, kb1); vLo <- V(t+1) low half
      if (t < SS / 64 - 1) {
#pragma unroll
        for (int m = 0; m < 4; ++m) kB[m] = LD16(Kl + tn + m * 1024 + 256);
#pragma unroll
        for (int jl = 0; jl < 2; ++jl)
#pragma unroll
          for (int vb = 0; vb < 2; ++vb)
            vLo[2 * jl + vb] = LD16(Vl + tn + jl * 1024 + vb * 256);
      }
      SM_CLUSTER(sc0, sc1);
    }
  }

  // drain: PV(kb1 of last tile, vHi = V(last))
  __builtin_amdgcn_s_setprio(1);
  PV_CLUSTER(vHi);
  __builtin_amdgcn_s_setprio(0);

  // combine the two k-halves' partial sums (lanes l and l+32 share q)
  lsum0 += __shfl_xor(lsum0, 32, 64);
  lsum1 += __shfl_xor(lsum1, 32, 64);
  if (h == 0) {
    Lw[w][q31] = 1.0f / lsum0;
    Lw[w][32 + q31] = 1.0f / lsum1;
  }

  const int b = bh >> 4, head = bh & 15;
#pragma unroll
  for (int f = 0; f < 2; ++f) {
    f32x4 li[4];
#pragma unroll
    for (int rq = 0; rq < 4; ++rq)
      li[rq] = *reinterpret_cast<const f32x4*>(&Lw[w][32 * f + 8 * rq + 4 * h]);
    f16* aobase = AO + ((size_t)(b * SS + q0 + 64 * w + 32 * f)) * DD + head * 64 + q31;
#pragma unroll
    for (int vb = 0; vb < 2; ++vb)
#pragma unroll
      for (int reg = 0; reg < 16; ++reg) {
        int q = (reg & 3) + 8 * (reg >> 2) + 4 * h;
        aobase[(size_t)q * DD + 32 * vb] = (f16)(oacc[f][vb][reg] * li[reg >> 2][reg & 3]);
      }
  }
#undef PV_CLUSTER
#undef SM_CLUSTER
#undef LD16
}

// ---------------- launch ----------------
extern "C" void kernel_launch(void* const* d_in, const int* in_sizes, int n_in,
                              void* d_out, int out_size, void* d_ws, size_t ws_size,
                              hipStream_t stream) {
  (void)in_sizes; (void)n_in; (void)out_size; (void)ws_size;
  const float* x  = (const float*)d_in[0];
  const float* wq = (const float*)d_in[1];
  const float* bq = (const float*)d_in[2];
  const float* wk = (const float*)d_in[3];
  const float* bk = (const float*)d_in[4];
  const float* wv = (const float*)d_in[5];
  const float* bv = (const float*)d_in[6];
  const float* wo = (const float*)d_in[7];
  const float* bo = (const float*)d_in[8];
  float* out = (float*)d_out;

  char* ws = (char*)d_ws;
  f16* xh  = (f16*)ws; ws += (size_t)MM * DD * 2;
  f16* wqh = (f16*)ws; ws += (size_t)DD * DD * 2;
  f16* wkh = (f16*)ws; ws += (size_t)DD * DD * 2;
  f16* wvh = (f16*)ws; ws += (size_t)DD * DD * 2;
  f16* woh = (f16*)ws; ws += (size_t)DD * DD * 2;
  f16* Qb  = (f16*)ws; ws += (size_t)MM * DD * 2;
  f16* Kb  = (f16*)ws; ws += (size_t)MM * DD * 2;
  f16* Vtb = (f16*)ws; ws += (size_t)MM * DD * 2;
  f16* AOb = (f16*)ws; ws += (size_t)MM * DD * 2;

  cvt_all_kernel<<<MM * DD / 4 / 256 + 4 * (DD * DD / 4 / 256), 256, 0, stream>>>(
      x, wq, wk, wv, wo, xh, wqh, wkh, wvh, woh);

  qkv_kernel<<<1536, 256, 0, stream>>>(xh, wqh, wkh, wvh, bq, bk, bv, Qb, Kb, Vtb);

  attn_kernel<<<512, 256, 0, stream>>>(Qb, Kb, Vtb, AOb);

  oproj_kernel<<<512, 256, 0, stream>>>(AOb, woh, bo, out);
}